// Round 10
// baseline (60.274 us; speedup 1.0000x reference)
//
#include <hip/hip_runtime.h>
#include <hip/hip_bf16.h>

typedef __attribute__((ext_vector_type(8)))  short bf16x8;
typedef __attribute__((ext_vector_type(16))) float f32x16;

#define I_N 256
#define T_N 256
#define L_N 32
#define E_N 128
#define P_N 49

// ---- pre-pass: pack text(B) + image(A) into 32x32x16 MFMA fragment order ----
// B frag [t*8+ks][lane][8]: col l = lane&31 (token), k = ks*16 + (lane>>5)*8 + j
// A frag [i*16 + pt*8 + ks][lane][8]: patch = pt*32 + (lane&31), same k map.
__global__ __launch_bounds__(256) void pack_all(const float* __restrict__ txt,
                                                const float* __restrict__ img,
                                                unsigned short* __restrict__ bpre,
                                                unsigned short* __restrict__ apre) {
    const int bid = blockIdx.x;
    if (bid < 512) {                                 // ---- text
        int gid  = bid * 256 + threadIdx.x;
        int lane = gid & 63;
        int ks   = (gid >> 6) & 7;
        int t    = gid >> 9;
        int l    = lane & 31;
        int e0   = ks * 16 + (lane >> 5) * 8;
        const float* src = txt + (t * L_N + l) * E_N + e0;
        union { unsigned short u[8]; bf16x8 v; } o;
        #pragma unroll
        for (int j = 0; j < 8; ++j) {
            __hip_bfloat16 h = __float2bfloat16(src[j]);
            o.u[j] = *reinterpret_cast<unsigned short*>(&h);
        }
        ((bf16x8*)bpre)[gid] = o.v;
    } else {                                         // ---- image
        int gid   = (bid - 512) * 256 + threadIdx.x;
        int lane  = gid & 63;
        int ks    = (gid >> 6) & 7;
        int pt    = (gid >> 9) & 1;
        int i     = gid >> 10;
        int patch = pt * 32 + (lane & 31);
        int e0    = ks * 16 + (lane >> 5) * 8;
        const float* src = img + i * (E_N * P_N) + e0 * P_N + patch;
        union { unsigned short u[8]; bf16x8 v; } o;
        #pragma unroll
        for (int j = 0; j < 8; ++j) {
            float x = (patch < P_N) ? src[j * P_N] : 0.0f;
            __hip_bfloat16 h = __float2bfloat16(x);
            o.u[j] = *reinterpret_cast<unsigned short*>(&h);
        }
        ((bf16x8*)apre)[gid] = o.v;
    }
}

// ---- main kernel: grid 768, 4 waves/block, NO LDS/barriers/shuffles. ----
// Wave owns image i; grid-strides texts t = r, r+12, ... (22 slots, last clamped).
// Per text: prefetched B loads -> 16 MFMA -> shuffle-free tree-max -> 256B store
// of per-lane half-maxes. Cross-lane reduce deferred to reduce_k.
__global__ __launch_bounds__(256, 2) void clip_mfma(
    const unsigned short* __restrict__ apre,
    const unsigned short* __restrict__ bpre,
    float* __restrict__ mws) {

    const int wid  = threadIdx.x >> 6;
    const int lane = threadIdx.x & 63;
    const int b    = blockIdx.x;           // 0..767
    const int r    = b % 12;               // text stride offset
    const int i    = (b / 12) * 4 + wid;   // image
    const bool lo32 = (lane < 32);

    // Pin image A-frags: 2 patch-tiles x 8 k-steps = 64 VGPRs.
    bf16x8 af[2][8];
    const bf16x8* ap = (const bf16x8*)apre + (size_t)i * 16 * 64;
    #pragma unroll
    for (int pt = 0; pt < 2; ++pt)
        #pragma unroll
        for (int ks = 0; ks < 8; ++ks)
            af[pt][ks] = ap[(pt * 8 + ks) * 64 + lane];

    const bf16x8* bp = (const bf16x8*)bpre;

    auto loadB = [&](bf16x8 (&bf)[8], int t) {
        const bf16x8* tb = bp + (size_t)t * 8 * 64;
        #pragma unroll
        for (int ks = 0; ks < 8; ++ks)
            bf[ks] = tb[ks * 64 + lane];
    };

    auto mfmaT = [&](f32x16& a0, f32x16& a1, bf16x8 (&bf)[8]) {
        #pragma unroll
        for (int rr = 0; rr < 16; ++rr) { a0[rr] = 0.0f; a1[rr] = 0.0f; }
        __builtin_amdgcn_s_setprio(1);
        #pragma unroll
        for (int ks = 0; ks < 8; ++ks) {
            a0 = __builtin_amdgcn_mfma_f32_32x32x16_bf16(af[0][ks], bf[ks], a0, 0, 0, 0);
            a1 = __builtin_amdgcn_mfma_f32_32x32x16_bf16(af[1][ks], bf[ks], a1, 0, 0, 0);
        }
        __builtin_amdgcn_s_setprio(0);
    };

    // Shuffle-free per-lane patch max (valid rows only), then 1 coalesced store.
    // C: col = lane&31 (token), row = (reg&3)+8*(reg>>2)+4*(lane>>5) per tile.
    // Tile1: regs 0..7 valid both halves; reg 8 lo-half only (patch 48).
    auto treeStore = [&](f32x16& a0, f32x16& a1, int t) {
        float x[8];
        #pragma unroll
        for (int q = 0; q < 8; ++q) x[q] = fmaxf(a0[2 * q], a0[2 * q + 1]);
        #pragma unroll
        for (int q = 0; q < 4; ++q) x[q] = fmaxf(x[q], x[q + 4]);
        float ma0 = fmaxf(fmaxf(x[0], x[1]), fmaxf(x[2], x[3]));
        float y[4];
        #pragma unroll
        for (int q = 0; q < 4; ++q) y[q] = fmaxf(a1[2 * q], a1[2 * q + 1]);
        float ma1 = fmaxf(fmaxf(y[0], y[1]), fmaxf(y[2], y[3]));
        float m = fmaxf(ma0, ma1);
        if (lo32) m = fmaxf(m, a1[8]);
        mws[((size_t)i * T_N + t) * 64 + lane] = m;
    };

    bf16x8 bfA[8], bfB[8];
    f32x16 aA0, aA1, aB0, aB1;

    loadB(bfA, r);
    #pragma unroll 1
    for (int k = 0; k < 22; k += 2) {
        int t0v = r + 12 * k;                            // <= 251, never clamps
        int t1v = r + 12 * (k + 1); if (t1v >= T_N) t1v -= 12;   // last slot clamp
        loadB(bfB, t1v);                 // prefetch under slot-A MFMA
        mfmaT(aA0, aA1, bfA);
        treeStore(aA0, aA1, t0v);        // hides under slot-B issue
        if (k + 2 < 22) loadB(bfA, r + 12 * (k + 2));    // <= 251, no clamp
        mfmaT(aB0, aB1, bfB);
        treeStore(aB0, aB1, t1v);        // clamped slot rewrites same value: benign
    }
}

// ---- final reduce: one wave per (i,t); 16MB L2-resident mws -> 2 outputs ----
__global__ __launch_bounds__(256) void reduce_k(
    const float* __restrict__ mws,
    const int*   __restrict__ tlen,
    const float* __restrict__ nlt,
    float*       __restrict__ out) {
    const int wid  = threadIdx.x >> 6;
    const int lane = threadIdx.x & 63;
    const int pair = blockIdx.x * 4 + wid;      // 0..65535
    const int i = pair >> 8, t = pair & 255;

    float v = mws[(size_t)pair * 64 + lane];
    v = fmaxf(v, __shfl_xor(v, 32));            // merge halves -> 49-patch max
    float s = v;
    #pragma unroll
    for (int off = 1; off <= 16; off <<= 1)
        s += __shfl_xor(s, off);                // sum over 32 token cols

    if (lane == 0) {
        float match = (s / (float)tlen[t]) * expf(nlt[0]);
        out[i * T_N + t]             = match;   // logits_per_image [I][T]
        out[I_N * T_N + t * I_N + i] = match;   // logits_per_text  [T][I]
    }
}

extern "C" void kernel_launch(void* const* d_in, const int* in_sizes, int n_in,
                              void* d_out, int out_size, void* d_ws, size_t ws_size,
                              hipStream_t stream) {
    const float* img  = (const float*)d_in[0];
    const float* txt  = (const float*)d_in[1];
    const int*   tlen = (const int*)d_in[2];
    const float* nlt  = (const float*)d_in[3];
    float*       out  = (float*)d_out;

    unsigned short* bpre = (unsigned short*)d_ws;                       // 2 MB
    unsigned short* apre = (unsigned short*)((char*)d_ws + (2u << 20)); // 4 MB
    float*          mws  = (float*)((char*)d_ws + (6u << 20));          // 17 MB

    pack_all<<<1536, 256, 0, stream>>>(txt, img, bpre, apre);
    clip_mfma<<<768, 256, 0, stream>>>(apre, bpre, mws);
    reduce_k<<<16384, 256, 0, stream>>>(mws, tlen, nlt, out);
}

// Round 11
// 45.871 us; speedup vs baseline: 1.3140x; 1.3140x over previous
//
#include <hip/hip_runtime.h>
#include <hip/hip_bf16.h>

typedef __attribute__((ext_vector_type(8)))  short bf16x8;
typedef __attribute__((ext_vector_type(16))) float f32x16;

#define I_N 256
#define T_N 256
#define L_N 32
#define E_N 128
#define P_N 49

// ---- pre-pass: pack text(B) + image(A) into 32x32x16 MFMA fragment order ----
// B frag [t*8+ks][lane][8]: col l = lane&31 (token), k = ks*16 + (lane>>5)*8 + j
// A frag [i*16 + pt*8 + ks][lane][8]: patch = pt*32 + (lane&31), same k map.
__global__ __launch_bounds__(256) void pack_all(const float* __restrict__ txt,
                                                const float* __restrict__ img,
                                                unsigned short* __restrict__ bpre,
                                                unsigned short* __restrict__ apre) {
    const int bid = blockIdx.x;
    if (bid < 512) {                                 // ---- text
        int gid  = bid * 256 + threadIdx.x;
        int lane = gid & 63;
        int ks   = (gid >> 6) & 7;
        int t    = gid >> 9;
        int l    = lane & 31;
        int e0   = ks * 16 + (lane >> 5) * 8;
        const float* src = txt + (t * L_N + l) * E_N + e0;
        union { unsigned short u[8]; bf16x8 v; } o;
        #pragma unroll
        for (int j = 0; j < 8; ++j) {
            __hip_bfloat16 h = __float2bfloat16(src[j]);
            o.u[j] = *reinterpret_cast<unsigned short*>(&h);
        }
        ((bf16x8*)bpre)[gid] = o.v;
    } else {                                         // ---- image
        int gid   = (bid - 512) * 256 + threadIdx.x;
        int lane  = gid & 63;
        int ks    = (gid >> 6) & 7;
        int pt    = (gid >> 9) & 1;
        int i     = gid >> 10;
        int patch = pt * 32 + (lane & 31);
        int e0    = ks * 16 + (lane >> 5) * 8;
        const float* src = img + i * (E_N * P_N) + e0 * P_N + patch;
        union { unsigned short u[8]; bf16x8 v; } o;
        #pragma unroll
        for (int j = 0; j < 8; ++j) {
            float x = (patch < P_N) ? src[j * P_N] : 0.0f;
            __hip_bfloat16 h = __float2bfloat16(x);
            o.u[j] = *reinterpret_cast<unsigned short*>(&h);
        }
        ((bf16x8*)apre)[gid] = o.v;
    }
}

// ---- main kernel: 512 blocks (2/CU), 4 waves/block, 2 IMAGES PER WAVE. ----
// One bf load feeds 32 MFMAs in 4 independent chains (2 img x 2 patch-tiles):
// halves B-load cost per MFMA, quarters dependent-chain stalls. All 4 waves of
// a block walk the same 16 texts -> B stays L1-hot. No LDS, no barriers.
__global__ __launch_bounds__(256, 2) void clip_mfma(
    const unsigned short* __restrict__ apre,
    const unsigned short* __restrict__ bpre,
    const int*   __restrict__ tlen,
    const float* __restrict__ nlt,
    float*       __restrict__ out) {

    const int wid   = threadIdx.x >> 6;
    const int lane  = threadIdx.x & 63;
    const int b     = blockIdx.x;              // 0..511
    const int tbase = (b >> 5) << 4;           // text group of 16
    const int i0    = (b & 31) * 8 + wid * 2;  // this wave's image pair
    const float scale = expf(nlt[0]);
    const bool  lo32  = (lane < 32);

    // Pin A-frags for 2 images: 2 x 2 patch-tiles x 8 k-steps = 128 regs.
    bf16x8 af[2][2][8];
    #pragma unroll
    for (int im = 0; im < 2; ++im) {
        const bf16x8* ap = (const bf16x8*)apre + (size_t)(i0 + im) * 16 * 64;
        #pragma unroll
        for (int pt = 0; pt < 2; ++pt)
            #pragma unroll
            for (int ks = 0; ks < 8; ++ks)
                af[im][pt][ks] = ap[(pt * 8 + ks) * 64 + lane];
    }

    const bf16x8* bp = (const bf16x8*)bpre;

    #pragma unroll 1
    for (int t = tbase; t < tbase + 16; ++t) {
        // 8 coalesced 16B loads (1KB/wave/frag), L1-hot across the block's waves.
        bf16x8 bf[8];
        const bf16x8* tb = bp + (size_t)t * 8 * 64;
        #pragma unroll
        for (int ks = 0; ks < 8; ++ks)
            bf[ks] = tb[ks * 64 + lane];

        f32x16 a00, a01, a10, a11;   // [img][patch-tile]
        #pragma unroll
        for (int rr = 0; rr < 16; ++rr) {
            a00[rr] = 0.0f; a01[rr] = 0.0f; a10[rr] = 0.0f; a11[rr] = 0.0f;
        }

        #pragma unroll
        for (int ks = 0; ks < 8; ++ks) {   // 4 independent 8-deep chains
            a00 = __builtin_amdgcn_mfma_f32_32x32x16_bf16(af[0][0][ks], bf[ks], a00, 0, 0, 0);
            a01 = __builtin_amdgcn_mfma_f32_32x32x16_bf16(af[0][1][ks], bf[ks], a01, 0, 0, 0);
            a10 = __builtin_amdgcn_mfma_f32_32x32x16_bf16(af[1][0][ks], bf[ks], a10, 0, 0, 0);
            a11 = __builtin_amdgcn_mfma_f32_32x32x16_bf16(af[1][1][ks], bf[ks], a11, 0, 0, 0);
        }

        // Per image: max over 49 patches, sum over 32 tokens, 2 output stores.
        // C: col = lane&31 (token), row = (reg&3)+8*(reg>>2)+4*(lane>>5).
        // Tile1: regs 0..7 valid both halves; reg 8 lo-half only (patch 48).
        #pragma unroll
        for (int im = 0; im < 2; ++im) {
            const f32x16& c0 = im ? a10 : a00;
            const f32x16& c1 = im ? a11 : a01;
            float m = c0[0];
            #pragma unroll
            for (int rr = 1; rr < 16; ++rr) m = fmaxf(m, c0[rr]);
            #pragma unroll
            for (int rr = 0; rr < 8; ++rr)  m = fmaxf(m, c1[rr]);
            m = fmaxf(m, lo32 ? c1[8] : -INFINITY);
            m = fmaxf(m, __shfl_xor(m, 32));        // merge halves -> 49-patch max
            float s = m;
            #pragma unroll
            for (int off = 1; off <= 16; off <<= 1)
                s += __shfl_xor(s, off);            // sum over 32 token cols
            if (lane == 0) {
                float match = (s / (float)tlen[t]) * scale;
                const int i = i0 + im;
                out[i * T_N + t]             = match;  // logits_per_image [I][T]
                out[I_N * T_N + t * I_N + i] = match;  // logits_per_text  [T][I]
            }
        }
    }
}

extern "C" void kernel_launch(void* const* d_in, const int* in_sizes, int n_in,
                              void* d_out, int out_size, void* d_ws, size_t ws_size,
                              hipStream_t stream) {
    const float* img  = (const float*)d_in[0];
    const float* txt  = (const float*)d_in[1];
    const int*   tlen = (const int*)d_in[2];
    const float* nlt  = (const float*)d_in[3];
    float*       out  = (float*)d_out;

    unsigned short* bpre = (unsigned short*)d_ws;                       // 2 MB
    unsigned short* apre = (unsigned short*)((char*)d_ws + (2u << 20)); // 4 MB

    pack_all<<<1536, 256, 0, stream>>>(txt, img, bpre, apre);
    clip_mfma<<<512, 256, 0, stream>>>(apre, bpre, tlen, nlt, out);
}